// Round 2
// baseline (1022.497 us; speedup 1.0000x reference)
//
#include <hip/hip_runtime.h>
#include <hip/hip_bf16.h>

#define USER_NUM 50000
#define ITEM_NUM 20000
#define NNODE    70000
#define DD       64
#define SCAN_T   1024

__device__ __forceinline__ float node_feat(const float* __restrict__ ue,
                                           const float* __restrict__ ie,
                                           int n, int d) {
    return (n < USER_NUM) ? ue[n * DD + d] : ie[(n - USER_NUM) * DD + d];
}

// ---- CSR build: histogram -> block scan -> scatter -------------------------

__global__ __launch_bounds__(256) void hist_kernel(const int* __restrict__ erow,
                                                   int* __restrict__ cnt, int E) {
    const int stride = gridDim.x * blockDim.x;
    for (int e = blockIdx.x * blockDim.x + threadIdx.x; e < E; e += stride)
        atomicAdd(&cnt[erow[e]], 1);
}

__global__ __launch_bounds__(SCAN_T) void scan_kernel(const int* __restrict__ cnt,
                                                      int* __restrict__ base) {
    __shared__ int s[SCAN_T];
    const int t = threadIdx.x;
    const int CH = (NNODE + SCAN_T - 1) / SCAN_T;   // 69
    const int lo = t * CH;
    const int hi = min(lo + CH, NNODE);
    int sum = 0;
    for (int i = lo; i < hi; ++i) sum += cnt[i];
    s[t] = sum;
    __syncthreads();
    // inclusive Hillis-Steele scan over SCAN_T partials
    for (int off = 1; off < SCAN_T; off <<= 1) {
        int v = s[t];
        int u = (t >= off) ? s[t - off] : 0;
        __syncthreads();
        s[t] = v + u;
        __syncthreads();
    }
    int running = s[t] - sum;                       // exclusive start of my chunk
    for (int i = lo; i < hi; ++i) {
        base[i] = running;
        running += cnt[i];
    }
    if (t == SCAN_T - 1) base[NNODE] = s[SCAN_T - 1];
}

__global__ __launch_bounds__(256) void scatter_kernel(
    const int* __restrict__ erow, const int* __restrict__ ecol,
    const float* __restrict__ eval, const int* __restrict__ base,
    int* __restrict__ cursor, int2* __restrict__ epair, int E) {
    const int stride = gridDim.x * blockDim.x;
    for (int e = blockIdx.x * blockDim.x + threadIdx.x; e < E; e += stride) {
        const int r = erow[e];
        const int pos = atomicAdd(&cursor[r], 1);
        epair[base[r] + pos] = make_int2(ecol[e], __float_as_int(eval[e]));
    }
}

// ---- Fused SpMM (gather form, no atomics) + GCN transform ------------------
// One wave per row r: acc1 = sum v*f_c, acc2 = sum v*f_c^2, then
// h[r] = leaky_relu((acc1 + f_r) @ Wg1 + bg1 + acc2 @ Wg2 + bg2)

__global__ __launch_bounds__(256) void spmm_xform_kernel(
    const float* __restrict__ ue, const float* __restrict__ ie,
    const int2* __restrict__ epair, const int* __restrict__ base,
    const float* __restrict__ Wg1, const float* __restrict__ bg1,
    const float* __restrict__ Wg2, const float* __restrict__ bg2,
    float* __restrict__ h) {
    __shared__ float sW1[DD * DD];
    __shared__ float sW2[DD * DD];
    for (int i = threadIdx.x; i < DD * DD; i += 256) {
        sW1[i] = Wg1[i];
        sW2[i] = Wg2[i];
    }
    __syncthreads();
    const int lane = threadIdx.x & 63;
    const int wave = (int)((blockIdx.x * blockDim.x + threadIdx.x) >> 6);
    const int nw   = (int)((gridDim.x * blockDim.x) >> 6);
    for (int r = wave; r < NNODE; r += nw) {
        const int jb = base[r];
        const int je = base[r + 1];
        float acc1 = 0.f, acc2 = 0.f;
        for (int j = jb; j < je; ++j) {
            const int2 p = epair[j];
            const float v = __int_as_float(p.y);
            const float f = node_feat(ue, ie, p.x, lane);
            acc1 = fmaf(v, f, acc1);
            acc2 = fmaf(v * f, f, acc2);
        }
        const float a1 = acc1 + node_feat(ue, ie, r, lane);
        const float a2 = acc2;
        float o = bg1[lane] + bg2[lane];
#pragma unroll
        for (int k = 0; k < DD; ++k) {
            o = fmaf(__shfl(a1, k), sW1[k * DD + lane], o);
            o = fmaf(__shfl(a2, k), sW2[k * DD + lane], o);
        }
        h[r * DD + lane] = (o > 0.f) ? o : 0.01f * o;
    }
}

// ---- Gather + 3-layer MLP (W1 staged in LDS, embed kept in registers) ------

__global__ __launch_bounds__(256) void mlp_kernel(
    const float* __restrict__ ue, const float* __restrict__ ie,
    const float* __restrict__ h,
    const float* __restrict__ W1, const float* __restrict__ b1,
    const float* __restrict__ W2, const float* __restrict__ b2,
    const float* __restrict__ W3, const float* __restrict__ b3,
    const int* __restrict__ uid, const int* __restrict__ iid,
    float* __restrict__ out, int B) {
    __shared__ float sW1[4 * DD * DD];   // 64 KB: W1 is [256][64]
    __shared__ float sW2[DD * 32];
    __shared__ float sW3[32];
    for (int i = threadIdx.x; i < 4 * DD * DD; i += 256) sW1[i] = W1[i];
    for (int i = threadIdx.x; i < DD * 32; i += 256)     sW2[i] = W2[i];
    if (threadIdx.x < 32) sW3[threadIdx.x] = W3[threadIdx.x];
    __syncthreads();
    const int lane = threadIdx.x & 63;
    const int wave = (int)((blockIdx.x * blockDim.x + threadIdx.x) >> 6);
    const int nw   = (int)((gridDim.x * blockDim.x) >> 6);
    const float bias1 = b1[lane];
    const float bias2 = b2[lane & 31];
    const float w3v   = sW3[lane & 31];
    const float bias3 = b3[0];
    for (int s = wave; s < B; s += nw) {
        const int u  = uid[s];
        const int it = iid[s];
        const float r0 = ue[u * DD + lane];
        const float r1 = h[u * DD + lane];
        const float r2 = ie[it * DD + lane];
        const float r3 = h[(USER_NUM + it) * DD + lane];
        float acc = bias1;
#pragma unroll
        for (int k = 0; k < DD; ++k)
            acc = fmaf(__shfl(r0, k), sW1[k * DD + lane], acc);
#pragma unroll
        for (int k = 0; k < DD; ++k)
            acc = fmaf(__shfl(r1, k), sW1[(DD + k) * DD + lane], acc);
#pragma unroll
        for (int k = 0; k < DD; ++k)
            acc = fmaf(__shfl(r2, k), sW1[(2 * DD + k) * DD + lane], acc);
#pragma unroll
        for (int k = 0; k < DD; ++k)
            acc = fmaf(__shfl(r3, k), sW1[(3 * DD + k) * DD + lane], acc);
        const float o1 = (acc > 0.f) ? acc : 0.f;
        float acc2 = bias2;
#pragma unroll
        for (int k = 0; k < DD; ++k)
            acc2 = fmaf(__shfl(o1, k), sW2[k * 32 + (lane & 31)], acc2);
        const float o2 = (acc2 > 0.f) ? acc2 : 0.f;
        float p = o2 * w3v;
        p += __shfl_xor(p, 1);
        p += __shfl_xor(p, 2);
        p += __shfl_xor(p, 4);
        p += __shfl_xor(p, 8);
        p += __shfl_xor(p, 16);
        if (lane == 0) out[s] = p + bias3;
    }
}

extern "C" void kernel_launch(void* const* d_in, const int* in_sizes, int n_in,
                              void* d_out, int out_size, void* d_ws, size_t ws_size,
                              hipStream_t stream) {
    const float* ue   = (const float*)d_in[0];
    const float* ie   = (const float*)d_in[1];
    const int*   erow = (const int*)d_in[2];
    const int*   ecol = (const int*)d_in[3];
    const float* evalp= (const float*)d_in[4];
    const float* Wg1  = (const float*)d_in[5];
    const float* bg1  = (const float*)d_in[6];
    const float* Wg2  = (const float*)d_in[7];
    const float* bg2  = (const float*)d_in[8];
    const float* W1   = (const float*)d_in[9];
    const float* b1   = (const float*)d_in[10];
    const float* W2   = (const float*)d_in[11];
    const float* b2   = (const float*)d_in[12];
    const float* W3   = (const float*)d_in[13];
    const float* b3   = (const float*)d_in[14];
    const int*   uid  = (const int*)d_in[15];
    const int*   iid  = (const int*)d_in[16];
    float* out = (float*)d_out;

    const int E = in_sizes[2];
    const int B = in_sizes[15];

    // workspace layout
    char* ws = (char*)d_ws;
    const size_t nd = (size_t)NNODE * DD;                 // 4,480,000 floats
    float* h     = (float*)ws;                            // 17.92 MB
    int2*  epair = (int2*)(ws + nd * sizeof(float));      // E * 8 B
    int*   cnt   = (int*)(ws + nd * sizeof(float) + (size_t)E * sizeof(int2));
    int*   cursor= cnt + NNODE;
    int*   base  = cursor + NNODE;                        // NNODE + 1 ints

    hipMemsetAsync(cnt, 0, 2 * NNODE * sizeof(int), stream);

    hist_kernel<<<2048, 256, 0, stream>>>(erow, cnt, E);
    scan_kernel<<<1, SCAN_T, 0, stream>>>(cnt, base);
    scatter_kernel<<<2048, 256, 0, stream>>>(erow, ecol, evalp, base, cursor, epair, E);
    spmm_xform_kernel<<<1024, 256, 0, stream>>>(ue, ie, epair, base,
                                                Wg1, bg1, Wg2, bg2, h);
    mlp_kernel<<<768, 256, 0, stream>>>(ue, ie, h, W1, b1, W2, b2, W3, b3,
                                        uid, iid, out, B);
}

// Round 3
// 667.855 us; speedup vs baseline: 1.5310x; 1.5310x over previous
//
#include <hip/hip_runtime.h>
#include <hip/hip_bf16.h>

#define USER_NUM 50000
#define ITEM_NUM 20000
#define NNODE    70000
#define DD       64
#define SCAN_T   1024

__device__ __forceinline__ const float* feat_row(const float* __restrict__ ue,
                                                 const float* __restrict__ ie, int n) {
    return (n < USER_NUM) ? (ue + (size_t)n * DD)
                          : (ie + (size_t)(n - USER_NUM) * DD);
}

__device__ __forceinline__ float node_feat(const float* __restrict__ ue,
                                           const float* __restrict__ ie,
                                           int n, int d) {
    return (n < USER_NUM) ? ue[n * DD + d] : ie[(n - USER_NUM) * DD + d];
}

// ---- CSR build: histogram -> block scan -> scatter -------------------------

__global__ __launch_bounds__(256) void hist_kernel(const int* __restrict__ erow,
                                                   int* __restrict__ cnt, int E) {
    const int stride = gridDim.x * blockDim.x;
    for (int e = blockIdx.x * blockDim.x + threadIdx.x; e < E; e += stride)
        atomicAdd(&cnt[erow[e]], 1);
}

__global__ __launch_bounds__(SCAN_T) void scan_kernel(const int* __restrict__ cnt,
                                                      int* __restrict__ base) {
    __shared__ int s[SCAN_T];
    const int t = threadIdx.x;
    const int CH = (NNODE + SCAN_T - 1) / SCAN_T;   // 69
    const int lo = t * CH;
    const int hi = min(lo + CH, NNODE);
    int sum = 0;
    for (int i = lo; i < hi; ++i) sum += cnt[i];
    s[t] = sum;
    __syncthreads();
    for (int off = 1; off < SCAN_T; off <<= 1) {
        int v = s[t];
        int u = (t >= off) ? s[t - off] : 0;
        __syncthreads();
        s[t] = v + u;
        __syncthreads();
    }
    int running = s[t] - sum;
    for (int i = lo; i < hi; ++i) {
        base[i] = running;
        running += cnt[i];
    }
    if (t == SCAN_T - 1) base[NNODE] = s[SCAN_T - 1];
}

__global__ __launch_bounds__(256) void scatter_kernel(
    const int* __restrict__ erow, const int* __restrict__ ecol,
    const float* __restrict__ eval, const int* __restrict__ base,
    int* __restrict__ cursor, int2* __restrict__ epair, int E) {
    const int stride = gridDim.x * blockDim.x;
    for (int e = blockIdx.x * blockDim.x + threadIdx.x; e < E; e += stride) {
        const int r = erow[e];
        const int pos = atomicAdd(&cursor[r], 1);
        epair[base[r] + pos] = make_int2(ecol[e], __float_as_int(eval[e]));
    }
}

// ---- SpMM, gather form, scalarized edge stream -----------------------------
// One wave per row. Edge indices are wave-uniform -> s_load_dwordx2 for (c,v),
// feature gather is a coalesced global_load off an SGPR base.

__global__ __launch_bounds__(256) void spmm_kernel(
    const float* __restrict__ ue, const float* __restrict__ ie,
    const int2* __restrict__ epair, const int* __restrict__ base,
    float* __restrict__ lx, float* __restrict__ lx2) {
    const int lane = threadIdx.x & 63;
    int wv = (int)((blockIdx.x * blockDim.x + threadIdx.x) >> 6);
    wv = __builtin_amdgcn_readfirstlane(wv);
    const int nw = (int)((gridDim.x * blockDim.x) >> 6);
    for (int r = wv; r < NNODE; r += nw) {
        const int jb = base[r];
        const int je = base[r + 1];
        float acc1 = 0.f, acc2 = 0.f;
        int j = jb;
        for (; j + 4 <= je; j += 4) {
            const int2 p0 = epair[j + 0];
            const int2 p1 = epair[j + 1];
            const int2 p2 = epair[j + 2];
            const int2 p3 = epair[j + 3];
            const float f0 = feat_row(ue, ie, p0.x)[lane];
            const float f1 = feat_row(ue, ie, p1.x)[lane];
            const float f2 = feat_row(ue, ie, p2.x)[lane];
            const float f3 = feat_row(ue, ie, p3.x)[lane];
            const float v0 = __int_as_float(p0.y);
            const float v1 = __int_as_float(p1.y);
            const float v2 = __int_as_float(p2.y);
            const float v3 = __int_as_float(p3.y);
            acc1 = fmaf(v0, f0, acc1); acc2 = fmaf(v0 * f0, f0, acc2);
            acc1 = fmaf(v1, f1, acc1); acc2 = fmaf(v1 * f1, f1, acc2);
            acc1 = fmaf(v2, f2, acc1); acc2 = fmaf(v2 * f2, f2, acc2);
            acc1 = fmaf(v3, f3, acc1); acc2 = fmaf(v3 * f3, f3, acc2);
        }
        for (; j < je; ++j) {
            const int2 p = epair[j];
            const float f = feat_row(ue, ie, p.x)[lane];
            const float v = __int_as_float(p.y);
            acc1 = fmaf(v, f, acc1);
            acc2 = fmaf(v * f, f, acc2);
        }
        lx [(size_t)r * DD + lane] = acc1;
        lx2[(size_t)r * DD + lane] = acc2;
    }
}

// ---- GCN transform: h = leaky_relu((lx+f)@Wg1 + bg1 + lx2@Wg2 + bg2) -------
// NOTE: h aliases lx (each row is read by its owning wave before being written).

__global__ __launch_bounds__(256) void transform_kernel(
    const float* __restrict__ ue, const float* __restrict__ ie,
    const float* lx, const float* lx2,
    const float* __restrict__ Wg1, const float* __restrict__ bg1,
    const float* __restrict__ Wg2, const float* __restrict__ bg2,
    float* h) {
    __shared__ float sW1[DD * DD];
    __shared__ float sW2[DD * DD];
    for (int i = threadIdx.x; i < DD * DD; i += 256) {
        sW1[i] = Wg1[i];
        sW2[i] = Wg2[i];
    }
    __syncthreads();
    const int lane = threadIdx.x & 63;
    const int wave = (int)((blockIdx.x * blockDim.x + threadIdx.x) >> 6);
    const int nw   = (int)((gridDim.x * blockDim.x) >> 6);
    const float bias = bg1[lane] + bg2[lane];
    for (int n = wave; n < NNODE; n += nw) {
        const float f  = node_feat(ue, ie, n, lane);
        const float a1 = lx[(size_t)n * DD + lane] + f;
        const float a2 = lx2[(size_t)n * DD + lane];
        float o = bias;
#pragma unroll
        for (int k = 0; k < DD; ++k) {
            o = fmaf(__shfl(a1, k), sW1[k * DD + lane], o);
            o = fmaf(__shfl(a2, k), sW2[k * DD + lane], o);
        }
        h[(size_t)n * DD + lane] = (o > 0.f) ? o : 0.01f * o;
    }
}

// ---- Gather + 3-layer MLP --------------------------------------------------

__global__ __launch_bounds__(256) void mlp_kernel(
    const float* __restrict__ ue, const float* __restrict__ ie,
    const float* __restrict__ h,
    const float* __restrict__ W1, const float* __restrict__ b1,
    const float* __restrict__ W2, const float* __restrict__ b2,
    const float* __restrict__ W3, const float* __restrict__ b3,
    const int* __restrict__ uid, const int* __restrict__ iid,
    float* __restrict__ out, int B) {
    __shared__ float sW1[4 * DD * DD];   // 64 KB: W1 is [256][64]
    __shared__ float sW2[DD * 32];
    __shared__ float sW3[32];
    for (int i = threadIdx.x; i < 4 * DD * DD; i += 256) sW1[i] = W1[i];
    for (int i = threadIdx.x; i < DD * 32; i += 256)     sW2[i] = W2[i];
    if (threadIdx.x < 32) sW3[threadIdx.x] = W3[threadIdx.x];
    __syncthreads();
    const int lane = threadIdx.x & 63;
    const int wave = (int)((blockIdx.x * blockDim.x + threadIdx.x) >> 6);
    const int nw   = (int)((gridDim.x * blockDim.x) >> 6);
    const float bias1 = b1[lane];
    const float bias2 = b2[lane & 31];
    const float w3v   = sW3[lane & 31];
    const float bias3 = b3[0];
    for (int s = wave; s < B; s += nw) {
        const int u  = uid[s];
        const int it = iid[s];
        const float r0 = ue[u * DD + lane];
        const float r1 = h[(size_t)u * DD + lane];
        const float r2 = ie[it * DD + lane];
        const float r3 = h[(size_t)(USER_NUM + it) * DD + lane];
        float acc = bias1;
#pragma unroll
        for (int k = 0; k < DD; ++k)
            acc = fmaf(__shfl(r0, k), sW1[k * DD + lane], acc);
#pragma unroll
        for (int k = 0; k < DD; ++k)
            acc = fmaf(__shfl(r1, k), sW1[(DD + k) * DD + lane], acc);
#pragma unroll
        for (int k = 0; k < DD; ++k)
            acc = fmaf(__shfl(r2, k), sW1[(2 * DD + k) * DD + lane], acc);
#pragma unroll
        for (int k = 0; k < DD; ++k)
            acc = fmaf(__shfl(r3, k), sW1[(3 * DD + k) * DD + lane], acc);
        const float o1 = (acc > 0.f) ? acc : 0.f;
        float acc2 = bias2;
#pragma unroll
        for (int k = 0; k < DD; ++k)
            acc2 = fmaf(__shfl(o1, k), sW2[k * 32 + (lane & 31)], acc2);
        const float o2 = (acc2 > 0.f) ? acc2 : 0.f;
        float p = o2 * w3v;
        p += __shfl_xor(p, 1);
        p += __shfl_xor(p, 2);
        p += __shfl_xor(p, 4);
        p += __shfl_xor(p, 8);
        p += __shfl_xor(p, 16);
        if (lane == 0) out[s] = p + bias3;
    }
}

extern "C" void kernel_launch(void* const* d_in, const int* in_sizes, int n_in,
                              void* d_out, int out_size, void* d_ws, size_t ws_size,
                              hipStream_t stream) {
    const float* ue   = (const float*)d_in[0];
    const float* ie   = (const float*)d_in[1];
    const int*   erow = (const int*)d_in[2];
    const int*   ecol = (const int*)d_in[3];
    const float* evalp= (const float*)d_in[4];
    const float* Wg1  = (const float*)d_in[5];
    const float* bg1  = (const float*)d_in[6];
    const float* Wg2  = (const float*)d_in[7];
    const float* bg2  = (const float*)d_in[8];
    const float* W1   = (const float*)d_in[9];
    const float* b1   = (const float*)d_in[10];
    const float* W2   = (const float*)d_in[11];
    const float* b2   = (const float*)d_in[12];
    const float* W3   = (const float*)d_in[13];
    const float* b3   = (const float*)d_in[14];
    const int*   uid  = (const int*)d_in[15];
    const int*   iid  = (const int*)d_in[16];
    float* out = (float*)d_out;

    const int E = in_sizes[2];
    const int B = in_sizes[15];

    // workspace layout (h aliases lx):
    //   [lx 17.92MB][lx2 17.92MB][epair 16MB][cnt .28MB][cursor .28MB][base .28MB]
    char* ws = (char*)d_ws;
    const size_t nd = (size_t)NNODE * DD;                   // 4,480,000 floats
    float* lx    = (float*)ws;
    float* h     = lx;                                      // alias, see transform
    float* lx2   = lx + nd;
    int2*  epair = (int2*)(ws + 2 * nd * sizeof(float));
    int*   cnt   = (int*)(ws + 2 * nd * sizeof(float) + (size_t)E * sizeof(int2));
    int*   cursor= cnt + NNODE;
    int*   base  = cursor + NNODE;                          // NNODE + 1 ints

    hipMemsetAsync(cnt, 0, 2 * NNODE * sizeof(int), stream);

    hist_kernel<<<2048, 256, 0, stream>>>(erow, cnt, E);
    scan_kernel<<<1, SCAN_T, 0, stream>>>(cnt, base);
    scatter_kernel<<<2048, 256, 0, stream>>>(erow, ecol, evalp, base, cursor, epair, E);
    spmm_kernel<<<4096, 256, 0, stream>>>(ue, ie, epair, base, lx, lx2);
    transform_kernel<<<1024, 256, 0, stream>>>(ue, ie, lx, lx2, Wg1, bg1, Wg2, bg2, h);
    mlp_kernel<<<768, 256, 0, stream>>>(ue, ie, h, W1, b1, W2, b2, W3, b3,
                                        uid, iid, out, B);
}